// Round 1
// 1139.437 us; speedup vs baseline: 1.3405x; 1.3405x over previous
//
#include <hip/hip_runtime.h>
#include <cstdint>
#include <cstddef>

// Problem constants (B=4, S=2048, K=4096, N=11008, G=128)
#define M_DIM 8192
#define K_DIM 4096
#define N_DIM 11008
#define NT    (K_DIM / 64)   // 64 K-tiles of BK=64

typedef short bf16x8 __attribute__((ext_vector_type(8)));
typedef float f32x4  __attribute__((ext_vector_type(4)));
typedef unsigned short us8 __attribute__((ext_vector_type(8)));

__device__ __forceinline__ unsigned short f2bf(float f) {
  unsigned int u = __float_as_uint(f);
  u += 0x7FFFu + ((u >> 16) & 1u);
  return (unsigned short)(u >> 16);
}

// ---------------- kernel 1: x fp32 -> bf16 ----------------
__global__ __launch_bounds__(256) void cvt_x_kernel(const float* __restrict__ x,
                                                    unsigned short* __restrict__ xb) {
  const int i = blockIdx.x * 256 + threadIdx.x;
  const float4* x4 = (const float4*)x;
  float4 a = x4[(size_t)i * 2];
  float4 b = x4[(size_t)i * 2 + 1];
  us8 o;
  o[0] = f2bf(a.x); o[1] = f2bf(a.y); o[2] = f2bf(a.z); o[3] = f2bf(a.w);
  o[4] = f2bf(b.x); o[5] = f2bf(b.y); o[6] = f2bf(b.z); o[7] = f2bf(b.w);
  *(us8*)(xb + (size_t)i * 8) = o;
}

// ---------------- kernel 2: dequant int4 -> bf16 W^T (N x K) ----------------
__global__ __launch_bounds__(256) void dequant_kernel(const int* __restrict__ qw,
                                                      const float* __restrict__ sc,
                                                      unsigned short* __restrict__ wt) {
  const int n0 = blockIdx.x * 64;
  const int k0 = blockIdx.y * 64;
  const int g  = blockIdx.y >> 1;
  __shared__ unsigned short lds[64 * 64];
  const int t = threadIdx.x;
  {
    const int kk_l = t >> 5;
    const int n_l  = (t & 31) * 2;
    const int2  q2 = *(const int2*)&qw[(k0 / 8 + kk_l) * N_DIM + n0 + n_l];
    const float2 s2 = *(const float2*)&sc[g * N_DIM + n0 + n_l];
    us8 o0, o1;
#pragma unroll
    for (int j = 0; j < 8; ++j) {
      o0[j] = f2bf((float)(((q2.x >> (4 * j)) & 15) - 8) * s2.x);
      o1[j] = f2bf((float)(((q2.y >> (4 * j)) & 15) - 8) * s2.y);
    }
    *(us8*)&lds[(n_l    ) * 64 + kk_l * 8] = o0;
    *(us8*)&lds[(n_l + 1) * 64 + kk_l * 8] = o1;
  }
  __syncthreads();
#pragma unroll
  for (int it = 0; it < 2; ++it) {
    const int idx = t + it * 256;
    const int n_l = idx >> 3;
    const int ch  = (idx & 7) * 8;
    *(us8*)&wt[(size_t)(n0 + n_l) * K_DIM + k0 + ch] = *(const us8*)&lds[n_l * 64 + ch];
  }
}

// ---------------- kernel 3: 256x256 8-phase bf16 MFMA GEMM (m201 structure) ----
// A:(M,K) bf16 rm. Bt:(N,K) bf16 rm. C:(M,N) fp32.
// 512 thr = 8 waves (2Mx4N), per-wave 128x64 out, BK=64 split in two K-halves.
// LDS: 8 regions of 16KB = {A,B} x {dbuf} x {khalf}; region = [256 rows][32 bf16].
// Swizzle: phys 16B-chunk = logical_chunk ^ ((row>>1)&3)  (both on stage-src & ds_read).
// Per tile: 4 phases; stage targets P1:A[t+1]h1 P2:B[t+1]h1 P3:A[t+2]h0 P4:B[t+2]h0;
// one s_waitcnt vmcnt(4) per tile (tail: vmcnt(0)).
__global__ __launch_bounds__(512, 2) void gemm_kernel(const unsigned short* __restrict__ A,
                                                      const unsigned short* __restrict__ Bt,
                                                      float* __restrict__ C) {
  __shared__ unsigned short lds[8][8192];   // [0..3]=A(buf,h), [4..7]=B(buf,h)
  const int t    = threadIdx.x;
  const int wave = t >> 6;
  const int lane = t & 63;
  const int l15  = lane & 15;
  const int wr   = wave >> 2;    // 0..1
  const int wc   = wave & 3;     // 0..3

  // T1: bijective XCD swizzle (grid 1376 = 8*172)
  const int bid = blockIdx.x;
  const int wg  = (bid & 7) * 172 + (bid >> 3);
  const int m0  = (wg / 43) * 256;
  const int n0  = (wg % 43) * 256;

  // staging: thread t covers region rows (t>>2)+128j, phys chunk (t&3); pre-swizzle src chunk
  const int sq = (t & 3) ^ ((t >> 3) & 3);
  const unsigned short* gA = A  + (size_t)(m0 + (t >> 2)) * K_DIM + sq * 8;
  const unsigned short* gB = Bt + (size_t)(n0 + (t >> 2)) * K_DIM + sq * 8;

  // ds_read: row r -> ushort off r*32 + ((q ^ ((r>>1)&3))<<3); q=lane>>4; (r>>1)&3 == (l15>>1)&3
  const int sxo   = ((lane >> 4) ^ ((l15 >> 1) & 3)) << 3;
  const int aoffA = (wr * 128 + l15) * 32 + sxo;
  const int aoffB = (wc * 64  + l15) * 32 + sxo;

  auto stage = [&](const unsigned short* gbase, unsigned short* reg, int h, int tk) {
#pragma unroll
    for (int j = 0; j < 2; ++j) {
      __builtin_amdgcn_global_load_lds(
          (const __attribute__((address_space(1))) unsigned int*)(gbase + (size_t)j * 128 * K_DIM + tk * 64 + h * 32),
          (__attribute__((address_space(3))) unsigned int*)(reg + j * 4096 + t * 8),
          16, 0, 0);
    }
  };

  f32x4 acc[8][4] = {};

  // ---- prologue: tile0 all 4 regions + tile1 h0 pair (12 issues), retire 8 ----
  stage(gA, &lds[0][0], 0, 0);
  stage(gB, &lds[4][0], 0, 0);
  stage(gA, &lds[1][0], 1, 0);
  stage(gB, &lds[5][0], 1, 0);
  stage(gA, &lds[2][0], 0, 1);
  stage(gB, &lds[6][0], 0, 1);
  asm volatile("s_waitcnt vmcnt(4)" ::: "memory");
  __builtin_amdgcn_s_barrier();

#pragma unroll 1
  for (int tk = 0; tk < NT; ++tk) {
    const int p = tk & 1;
    const unsigned short* Ah0 = &lds[p * 2 + 0][0];
    const unsigned short* Ah1 = &lds[p * 2 + 1][0];
    const unsigned short* Bh0 = &lds[4 + p * 2 + 0][0];
    const unsigned short* Bh1 = &lds[4 + p * 2 + 1][0];
    unsigned short* stA1 = &lds[(p ^ 1) * 2 + 1][0];      // A[t+1] h1
    unsigned short* stB1 = &lds[4 + (p ^ 1) * 2 + 1][0];  // B[t+1] h1
    unsigned short* stA2 = &lds[p * 2 + 0][0];            // A[t+2] h0
    unsigned short* stB2 = &lds[4 + p * 2 + 0][0];        // B[t+2] h0

    bf16x8 a[4], b[4], a2[4];

    // ---- P1: h0, m-half 0 ----
#pragma unroll
    for (int i = 0; i < 4; ++i) a[i] = *(const bf16x8*)&Ah0[aoffA + i * 512];
#pragma unroll
    for (int i = 0; i < 4; ++i) b[i] = *(const bf16x8*)&Bh0[aoffB + i * 512];
    if (tk + 1 < NT) stage(gA, stA1, 1, tk + 1);
    __builtin_amdgcn_s_barrier();
    __builtin_amdgcn_s_setprio(1);
#pragma unroll
    for (int mi = 0; mi < 4; ++mi)
#pragma unroll
      for (int ni = 0; ni < 4; ++ni)
        acc[mi][ni] = __builtin_amdgcn_mfma_f32_16x16x32_bf16(a[mi], b[ni], acc[mi][ni], 0, 0, 0);
    __builtin_amdgcn_s_setprio(0);
    __builtin_amdgcn_s_barrier();

    // ---- P2: h0, m-half 1 (b reused) ----
#pragma unroll
    for (int i = 0; i < 4; ++i) a2[i] = *(const bf16x8*)&Ah0[aoffA + (i + 4) * 512];
    if (tk + 1 < NT) stage(gB, stB1, 1, tk + 1);
    __builtin_amdgcn_s_barrier();
    __builtin_amdgcn_s_setprio(1);
#pragma unroll
    for (int mi = 0; mi < 4; ++mi)
#pragma unroll
      for (int ni = 0; ni < 4; ++ni)
        acc[mi + 4][ni] = __builtin_amdgcn_mfma_f32_16x16x32_bf16(a2[mi], b[ni], acc[mi + 4][ni], 0, 0, 0);
    __builtin_amdgcn_s_setprio(0);
    __builtin_amdgcn_s_barrier();

    // ---- P3: h1, m-half 0 ----
#pragma unroll
    for (int i = 0; i < 4; ++i) a[i] = *(const bf16x8*)&Ah1[aoffA + i * 512];
#pragma unroll
    for (int i = 0; i < 4; ++i) b[i] = *(const bf16x8*)&Bh1[aoffB + i * 512];
    if (tk + 2 < NT) stage(gA, stA2, 0, tk + 2);
    __builtin_amdgcn_s_barrier();
    __builtin_amdgcn_s_setprio(1);
#pragma unroll
    for (int mi = 0; mi < 4; ++mi)
#pragma unroll
      for (int ni = 0; ni < 4; ++ni)
        acc[mi][ni] = __builtin_amdgcn_mfma_f32_16x16x32_bf16(a[mi], b[ni], acc[mi][ni], 0, 0, 0);
    __builtin_amdgcn_s_setprio(0);
    __builtin_amdgcn_s_barrier();

    // ---- P4: h1, m-half 1 ----
#pragma unroll
    for (int i = 0; i < 4; ++i) a2[i] = *(const bf16x8*)&Ah1[aoffA + (i + 4) * 512];
    if (tk + 2 < NT) stage(gB, stB2, 0, tk + 2);
    __builtin_amdgcn_s_barrier();
    __builtin_amdgcn_s_setprio(1);
#pragma unroll
    for (int mi = 0; mi < 4; ++mi)
#pragma unroll
      for (int ni = 0; ni < 4; ++ni)
        acc[mi + 4][ni] = __builtin_amdgcn_mfma_f32_16x16x32_bf16(a2[mi], b[ni], acc[mi + 4][ni], 0, 0, 0);
    __builtin_amdgcn_s_setprio(0);
    // tile boundary: retire tile t+1's 4 regions; keep t+2's h0 pair (4 loads) in flight
    if (tk + 2 < NT)      { asm volatile("s_waitcnt vmcnt(4)" ::: "memory"); }
    else if (tk + 1 < NT) { asm volatile("s_waitcnt vmcnt(0)" ::: "memory"); }
    __builtin_amdgcn_s_barrier();
  }

  // ---- epilogue: C/D layout col=lane&15, row=(lane>>4)*4+reg ----
  const int cn = n0 + wc * 64 + l15;
  const int rm = m0 + wr * 128 + (lane >> 4) * 4;
#pragma unroll
  for (int mi = 0; mi < 8; ++mi)
#pragma unroll
    for (int ni = 0; ni < 4; ++ni)
#pragma unroll
      for (int r = 0; r < 4; ++r)
        C[(size_t)(rm + mi * 16 + r) * N_DIM + cn + ni * 16] = acc[mi][ni][r];
}

extern "C" void kernel_launch(void* const* d_in, const int* in_sizes, int n_in,
                              void* d_out, int out_size, void* d_ws, size_t ws_size,
                              hipStream_t stream) {
  const float* x  = (const float*)d_in[0];
  const int*   qw = (const int*)d_in[1];
  const float* sc = (const float*)d_in[2];
  float* out = (float*)d_out;

  unsigned short* xb = (unsigned short*)d_ws;                                      // 64 MB
  unsigned short* wt = (unsigned short*)((char*)d_ws + (size_t)M_DIM * K_DIM * 2); // +86 MB

  cvt_x_kernel<<<dim3(M_DIM * K_DIM / (8 * 256)), dim3(256), 0, stream>>>(x, xb);
  dequant_kernel<<<dim3(N_DIM / 64, K_DIM / 64), dim3(256), 0, stream>>>(qw, sc, wt);
  gemm_kernel<<<dim3((N_DIM / 256) * (M_DIM / 256)), dim3(512), 0, stream>>>(xb, wt, out);
}